// Round 1
// baseline (62.679 us; speedup 1.0000x reference)
//
#include <hip/hip_runtime.h>

#define N_T 50

__device__ __forceinline__ float tanh_fast(float x) {
    // tanh(x) = (1 - e^{-2x}) / (1 + e^{-2x}); clamp to avoid inf/inf
    x = fminf(20.0f, fmaxf(-20.0f, x));
    float e = __expf(-2.0f * x);
    return (1.0f - e) / (1.0f + e);
}

__global__ __launch_bounds__(256)
void cbf_kernel(const float* __restrict__ data, float* __restrict__ out, int n) {
    __shared__ float lds[256 * 15];
    const int tid  = threadIdx.x;
    const int base = blockIdx.x * 256;
    const int cnt  = min(256, n - base);          // threads with real work
    // coalesced staging: contiguous 15*cnt floats for this block
    {
        const float* src = data + (long long)base * 15;
        const int total = cnt * 15;
        for (int k = tid; k < total; k += 256) lds[k] = src[k];
    }
    __syncthreads();
    if (tid >= cnt) return;
    const float* d = &lds[tid * 15];   // stride 15 (odd) -> conflict-free

    float ex = d[0],  ey = d[1],  ev = d[2],  eth = d[3];
    float ax = d[4],  ay = d[5],  av = d[6],  ath = d[7];
    float eex = d[8], eey = d[9];                 // ego extent x,y
    float aex = d[11], aey = d[12];               // agent extent x,y
    float dt = d[14];

    const float r_ag = 0.5f * sqrtf(aex * aex + aey * aey);
    const float r_eg = 0.5f * sqrtf(eex * eex + eey * eey);
    const float hex = 0.5f * eex, hey = 0.5f * eey;
    const float hax = 0.5f * aex, hay = 0.5f * aey;

    // heading is constant (turn == 0): hoist sincos out of the loop
    float ce, se; __sincosf(eth, &se, &ce);
    float ca, sa; __sincosf(ath, &sa, &ca);

    float hmin = 3.4e38f;
    #pragma unroll 2
    for (int t = 0; t < N_T; ++t) {
        // braking controller from PRE-update v
        float bke = -9.0f * tanh_fast(2.0f * ev);
        float bka = -9.0f * tanh_fast(2.0f * av);
        // unicycle step (positions use pre-update v)
        ex = fmaf(dt * ev, ce, ex);
        ey = fmaf(dt * ev, se, ey);
        ax = fmaf(dt * av, ca, ax);
        ay = fmaf(dt * av, sa, ay);
        ev = fmaf(dt, bke, ev);
        av = fmaf(dt, bka, av);

        // distance on POST-update state; "angle" is state[...,2] == v
        float dx = ax - ex, dy = ay - ey;
        float c1, s1; __sincosf(ev, &s1, &c1);
        float c2, s2; __sincosf(av, &s2, &c2);
        // rel1 = rotate2d((dx,dy), -ev)
        float rx1 = fmaf(c1, dx,  s1 * dy);
        float ry1 = fmaf(c1, dy, -s1 * dx);
        // rel2 = rotate2d((-dx,-dy), -av)
        float rx2 = fmaf(-c2, dx, -s2 * dy);
        float ry2 = fmaf(c2, -dy,  s2 * dx);

        float d1 = fmaxf(fabsf(rx1) - hex, fabsf(ry1) - hey) - r_ag;
        float d2 = fmaxf(fabsf(rx2) - hax, fabsf(ry2) - hay) - r_eg;
        hmin = fminf(hmin, fmaxf(d1, d2));
    }

    // (sigmoid(h/5) - 0.5) * 2 * 5 == 5 * tanh(h/10)
    out[base + tid] = 5.0f * tanh_fast(0.1f * hmin);
}

extern "C" void kernel_launch(void* const* d_in, const int* in_sizes, int n_in,
                              void* d_out, int out_size, void* d_ws, size_t ws_size,
                              hipStream_t stream) {
    const float* data = (const float*)d_in[0];
    float* out = (float*)d_out;
    const int n = in_sizes[0] / 15;               // B*A elements
    const int blocks = (n + 255) / 256;
    cbf_kernel<<<blocks, 256, 0, stream>>>(data, out, n);
}

// Round 2
// 60.268 us; speedup vs baseline: 1.0400x; 1.0400x over previous
//
#include <hip/hip_runtime.h>

#define N_T 50

// tanh(2v) = (1 - e^{-4v}) / (1 + e^{-4v}), div via v_rcp_f32.
// Clamp exp arg upper side only (e -> +inf would give NaN through rcp;
// underflow to 0 is exact).
__device__ __forceinline__ float tanh2_fast(float v) {
    float e = __expf(fminf(-4.0f * v, 80.0f));
    return (1.0f - e) * __builtin_amdgcn_rcpf(1.0f + e);
}

__global__ __launch_bounds__(256)
void cbf_kernel(const float* __restrict__ data, float* __restrict__ out, int n) {
    const int EPB = 128;                       // elements per 256-thread block
    __shared__ float lds[EPB * 15];
    const int tid   = threadIdx.x;
    const int ebase = blockIdx.x * EPB;
    const int cnt   = min(EPB, n - ebase);
    {   // coalesced staging of this block's 15-float records
        const float* src = data + (long long)ebase * 15;
        const int total = cnt * 15;
        for (int k = tid; k < total; k += 256) lds[k] = src[k];
    }
    __syncthreads();

    const int e   = tid >> 1;                  // element within block
    const int odd = tid & 1;                   // 0 = ego, 1 = agent
    if (e >= cnt) return;
    const float* d  = &lds[e * 15];            // stride 15 (odd) -> conflict-light
    const float* st = d + odd * 4;             // own vehicle state
    const float* xt = d + 8 + odd * 3;         // own extent

    float x  = st[0], y = st[1], v = st[2], th = st[3];
    float ex = xt[0], ey = xt[1];
    float dt = d[14];

    const float hx = 0.5f * ex, hy = 0.5f * ey;
    const float r_self    = 0.5f * sqrtf(ex * ex + ey * ey);
    const float r_partner = __shfl_xor(r_self, 1);

    // heading constant (turn==0): hoist sincos, fold dt
    const float kc   = dt * __cosf(th);
    const float ks   = dt * __sinf(th);
    const float n9dt = -9.0f * dt;

    float hmin = 3.4e38f;
    #pragma unroll 2
    for (int t = 0; t < N_T; ++t) {
        float tb = tanh2_fast(v);              // brake/-9 from PRE-update v
        x = fmaf(v, kc, x);                    // positions use pre-update v
        y = fmaf(v, ks, y);
        v = fmaf(n9dt, tb, v);                 // post-update v = rotation angle

        float px = __shfl_xor(x, 1);
        float py = __shfl_xor(y, 1);
        float dx = px - x, dy = py - y;        // partner - self (both sides)

        float sv = __sinf(v), cv = __cosf(v);
        // rotate2d(partner-self, -v)
        float rx = fmaf(cv, dx,  sv * dy);
        float ry = fmaf(cv, dy, -sv * dx);

        float ds_ = fmaxf(fabsf(rx) - hx, fabsf(ry) - hy) - r_partner;
        float dp  = fmaxf(ds_, __shfl_xor(ds_, 1));   // max(dis1, dis2)
        hmin = fminf(hmin, dp);
    }

    if (!odd) {
        // (sigmoid(h/5)-0.5)*2*5 == 5*tanh(h/10)
        float e2 = __expf(fminf(-0.2f * hmin, 80.0f));
        out[ebase + e] = 5.0f * (1.0f - e2) * __builtin_amdgcn_rcpf(1.0f + e2);
    }
}

extern "C" void kernel_launch(void* const* d_in, const int* in_sizes, int n_in,
                              void* d_out, int out_size, void* d_ws, size_t ws_size,
                              hipStream_t stream) {
    const float* data = (const float*)d_in[0];
    float* out = (float*)d_out;
    const int n = in_sizes[0] / 15;            // B*A elements
    const int EPB = 128;
    const int blocks = (n + EPB - 1) / EPB;
    cbf_kernel<<<blocks, 256, 0, stream>>>(data, out, n);
}